// Round 1
// baseline (290.399 us; speedup 1.0000x reference)
//
#include <hip/hip_runtime.h>

#define HH 96
#define WW 96
#define DD 16
#define NG 512
#define NF 32
#define NP (HH * WW * DD)   // 147456 points

// Per-gaussian packed params in d_ws: 12 floats each
// [mx,my,mz, a00,a01,a02,a11,a12,a22, opacity, pad, pad]

__global__ __launch_bounds__(256) void gr_prep(
    const float* __restrict__ means,
    const float* __restrict__ scales,
    const float* __restrict__ rots,
    const float* __restrict__ opac,
    const float* __restrict__ cam,
    float* __restrict__ gp)
{
    int n = blockIdx.x * blockDim.x + threadIdx.x;
    if (n >= NG) return;

    float mx = means[n * 3 + 0];
    float my = means[n * 3 + 1];
    float mz = means[n * 3 + 2];

    // homo = [m,1] @ cam^T  ->  homo_i = cam[i][0]*mx + cam[i][1]*my + cam[i][2]*mz + cam[i][3]
    float h0 = cam[0]  * mx + cam[1]  * my + cam[2]  * mz + cam[3];
    float h1 = cam[4]  * mx + cam[5]  * my + cam[6]  * mz + cam[7];
    float h2 = cam[8]  * mx + cam[9]  * my + cam[10] * mz + cam[11];
    float h3 = cam[12] * mx + cam[13] * my + cam[14] * mz + cam[15];
    float ih3 = 1.0f / h3;
    mx = h0 * ih3; my = h1 * ih3; mz = h2 * ih3;

    float qw = rots[n * 4 + 0];
    float qx = rots[n * 4 + 1];
    float qy = rots[n * 4 + 2];
    float qz = rots[n * 4 + 3];
    float qinv = 1.0f / sqrtf(qw * qw + qx * qx + qy * qy + qz * qz);
    qw *= qinv; qx *= qinv; qy *= qinv; qz *= qinv;

    float R00 = 1.0f - 2.0f * (qy * qy + qz * qz);
    float R01 = 2.0f * (qx * qy - qw * qz);
    float R02 = 2.0f * (qx * qz + qw * qy);
    float R10 = 2.0f * (qx * qy + qw * qz);
    float R11 = 1.0f - 2.0f * (qx * qx + qz * qz);
    float R12 = 2.0f * (qy * qz - qw * qx);
    float R20 = 2.0f * (qx * qz - qw * qy);
    float R21 = 2.0f * (qy * qz + qw * qx);
    float R22 = 1.0f - 2.0f * (qx * qx + qy * qy);

    float s0 = scales[n * 3 + 0];
    float s1 = scales[n * 3 + 1];
    float s2 = scales[n * 3 + 2];
    // cov = R diag(s^2) R^T (R orthonormal) => inv_cov = R diag(s^-2) R^T
    float i0 = 1.0f / (s0 * s0);
    float i1 = 1.0f / (s1 * s1);
    float i2 = 1.0f / (s2 * s2);

    float a00 = R00 * R00 * i0 + R01 * R01 * i1 + R02 * R02 * i2;
    float a01 = R00 * R10 * i0 + R01 * R11 * i1 + R02 * R12 * i2;
    float a02 = R00 * R20 * i0 + R01 * R21 * i1 + R02 * R22 * i2;
    float a11 = R10 * R10 * i0 + R11 * R11 * i1 + R12 * R12 * i2;
    float a12 = R10 * R20 * i0 + R11 * R21 * i1 + R12 * R22 * i2;
    float a22 = R20 * R20 * i0 + R21 * R21 * i1 + R22 * R22 * i2;

    float* g = gp + n * 12;
    g[0] = mx;  g[1] = my;  g[2] = mz;
    g[3] = a00; g[4] = a01; g[5] = a02;
    g[6] = a11; g[7] = a12; g[8] = a22;
    g[9] = opac[n];
    g[10] = 0.0f; g[11] = 0.0f;
}

__global__ __launch_bounds__(256) void gr_render(
    const float* __restrict__ gp,
    const float* __restrict__ feats,
    const float* __restrict__ coords,
    float* __restrict__ out)
{
    int p = blockIdx.x * 256 + threadIdx.x;  // one thread per grid point
    float cx = coords[p * 3 + 0];
    float cy = coords[p * 3 + 1];
    float cz = coords[p * 3 + 2];

    float acc[NF];
#pragma unroll
    for (int j = 0; j < NF; ++j) acc[j] = 0.0f;

    float T = 1.0f;

    for (int n = 0; n < NG; ++n) {
        const float* __restrict__ g = gp + n * 12;
        float dx = cx - g[0];
        float dy = cy - g[1];
        float dz = cz - g[2];
        float t0 = g[3] * dx + g[4] * dy + g[5] * dz;
        float t1 = g[4] * dx + g[6] * dy + g[7] * dz;
        float t2 = g[5] * dx + g[7] * dy + g[8] * dz;
        float mahal = dx * t0 + dy * t1 + dz * t2;
        float alpha = g[9] * __expf(-0.5f * mahal);
        float wgt = T * alpha;
        T *= (1.0f - alpha);

        const float* __restrict__ f = feats + n * NF;
#pragma unroll
        for (int j = 0; j < NF; ++j) acc[j] = fmaf(wgt, f[j], acc[j]);
    }

    float* __restrict__ o = out + p * NF;
#pragma unroll
    for (int j = 0; j < NF; ++j) o[j] = acc[j];
}

extern "C" void kernel_launch(void* const* d_in, const int* in_sizes, int n_in,
                              void* d_out, int out_size, void* d_ws, size_t ws_size,
                              hipStream_t stream)
{
    const float* means  = (const float*)d_in[0];   // (512,3)
    const float* scales = (const float*)d_in[1];   // (512,3)
    const float* rots   = (const float*)d_in[2];   // (512,4)
    const float* opac   = (const float*)d_in[3];   // (512,1)
    const float* feats  = (const float*)d_in[4];   // (512,32)
    const float* cam    = (const float*)d_in[5];   // (4,4)
    const float* coords = (const float*)d_in[6];   // (96,96,16,3)
    float* out = (float*)d_out;                    // (96,96,16,32) fp32

    float* gp = (float*)d_ws;                      // 512*12 floats = 24 KiB

    gr_prep<<<(NG + 255) / 256, 256, 0, stream>>>(means, scales, rots, opac, cam, gp);
    gr_render<<<NP / 256, 256, 0, stream>>>(gp, feats, coords, out);
}